// Round 1
// baseline (275.548 us; speedup 1.0000x reference)
//
#include <hip/hip_runtime.h>

// Problem constants (fixed by setup_inputs)
#define S_LEN   2048
#define D_DIM   128
#define KH_N    4
#define QH_N    4
#define H_N     (KH_N * QH_N)
#define SINK_N  16
#define MAXW    160    // >= window(128) + sink(16)
#define MAXC    1904   // >= S - SINK - window
#define MAXT    2048   // unified list capacity (s+1 <= 2048)
#define NREG    16     // u32 regs, 2 fp16 ordered keys each -> 2048 entries
#define CHUNK   512    // rows scored per LDS chunk
#define MAXSEL  208    // window(144) + top_k(64)
#define PLANE32 676    // u32 per plane (676 % 32 == 4 -> bank-skewed);
                       // phase A: 256 u32 packed chunk keys
                       // phase B: hist 256 u32 | selq 208 u64 (@ +256)

typedef __attribute__((ext_vector_type(8))) _Float16 f16x8;
typedef __attribute__((ext_vector_type(2))) _Float16 f16x2;
typedef __attribute__((ext_vector_type(4))) float f32x4;

__device__ __forceinline__ void lds_fence() {
  asm volatile("s_waitcnt lgkmcnt(0)" ::: "memory");
}
__device__ __forceinline__ unsigned short f2h(float f) {
  _Float16 h = (_Float16)f;
  return __builtin_bit_cast(unsigned short, h);
}
// pack two fp32 -> two fp16 (RTZ) as u32
__device__ __forceinline__ unsigned int pkrtz_u32(float a, float b) {
  return __builtin_bit_cast(unsigned int, __builtin_amdgcn_cvt_pkrtz(a, b));
}
// pack two fp32 scores -> two 16-bit ordered keys (monotone with value)
__device__ __forceinline__ unsigned int pack_okey16(float a, float b) {
  unsigned int u = pkrtz_u32(a, b);
  unsigned int t = (u >> 15) & 0x00010001u;
  return u ^ ((t * 0x7FFFu) | 0x80008000u);
}
__device__ __forceinline__ float okinv16(unsigned int k) {  // k in low 16 bits
  unsigned short bits = (k & 0x8000u) ? (unsigned short)(k & 0x7FFFu)
                                      : (unsigned short)(~k & 0xFFFFu);
  return (float)__builtin_bit_cast(_Float16, bits);
}

// ---------------------------------------------------------------------------
// Kernel 1 (k/v only): one wave per 4 rows, row-type uniform per wave.
// [0,8192) k rows: sign words + fp16 plane. [8192,16384) v rows: fp16 plane.
// ---------------------------------------------------------------------------
__global__ __launch_bounds__(256) void pack_kernel(
    const float* __restrict__ k, const float* __restrict__ v,
    unsigned long long* __restrict__ signs,
    unsigned short* __restrict__ kf16, unsigned int* __restrict__ vf16) {
  const int wid  = (blockIdx.x * 256 + threadIdx.x) >> 6;
  const int lane = threadIdx.x & 63;
  const int rbase = wid * 4;
  const int KROWS = KH_N * S_LEN;           // 8192

  if (rbase < KROWS) {
    const float* src = k + (size_t)rbase * D_DIM;
    float a[4], b[4];
#pragma unroll
    for (int r = 0; r < 4; r++) {
      a[r] = src[r * D_DIM + lane];
      b[r] = src[r * D_DIM + 64 + lane];
    }
#pragma unroll
    for (int r = 0; r < 4; r++) {
      unsigned long long b0 = __ballot(a[r] >= 0.0f);
      unsigned long long b1 = __ballot(b[r] >= 0.0f);
      if (lane == 0) {
        signs[(size_t)(rbase + r) * 2]     = b0;
        signs[(size_t)(rbase + r) * 2 + 1] = b1;
      }
      unsigned short* rb = kf16 + (size_t)(rbase + r) * 128;
      rb[lane]      = f2h(a[r]);
      rb[64 + lane] = f2h(b[r]);
    }
  } else {
    int vr = rbase - KROWS;
    const float* src = v + (size_t)vr * D_DIM;
    float2 f2[4];
#pragma unroll
    for (int r = 0; r < 4; r++)
      f2[r] = *(const float2*)(src + r * D_DIM + lane * 2);
#pragma unroll
    for (int r = 0; r < 4; r++) {
      unsigned int pk = (unsigned int)f2h(f2[r].x) |
                        ((unsigned int)f2h(f2[r].y) << 16);
      vf16[(size_t)(vr + r) * 64 + lane] = pk;
    }
  }
}

// ---------------------------------------------------------------------------
// Kernel 2: one block (4 waves) per (kh, s); wave == qh within the GQA group.
// xcd swizzle (blockIdx&7) -> each kh owned by 2 XCDs (halved FETCH in r8).
// fp16 packed score keys: NREG=16, radix-256 in 2 passes.
// __launch_bounds__(256,5): ~102-reg cap; pipelined version needs ~80
// (no spill; watch WRITE_SIZE for spill evidence).
// r9: depth-1 software pipelining of the two gather loops (Stage 2 K-rows,
// Stage 5 V-rows) -- VALUBusy was 53% with all other pipes idle; the stall
// was load->use serial latency in these dynamic-trip-count loops.
// ---------------------------------------------------------------------------
__global__ __launch_bounds__(256, 5) void attn_kernel(
    const float* __restrict__ query, const float* __restrict__ thr,
    const int* __restrict__ p_topk, const int* __restrict__ p_wsz,
    const unsigned long long* __restrict__ signs,
    const unsigned short* __restrict__ kf16,
    const unsigned int* __restrict__ vf16,
    float* __restrict__ out) {
  const int xcd  = blockIdx.x & 7;
  const int kh   = xcd >> 1;
  const int s    = (S_LEN - 1) - (((blockIdx.x >> 3) << 1) | (xcd & 1));
  const int tid  = threadIdx.x;
  const int lane = tid & 63;
  const int qh   = tid >> 6;
  const int col  = lane & 15;
  const int quad = lane >> 4;

  __shared__ __align__(16) unsigned int buf[QH_N * PLANE32]; // 10816 B
  __shared__ __align__(16) unsigned short q_f16[QH_N][136];  // 1088 B
  __shared__ unsigned short idx_sh[MAXT];                    // 4096 B
  __shared__ unsigned long long qs_sh[QH_N][2];
  __shared__ int ncand_sh;

  const int   topk   = *p_topk;   // 64
  const int   wsz    = *p_wsz;    // 128
  const float thresh = thr[kh];   // 70.0
  const float scale  = 0.088388347648318447f;  // 1/sqrt(128)

  // ---- load q rows; build q_f16 + q sign words (ballot == sign word) ----
  {
    int h0 = tid >> 7, d = tid & 127;
    float f0 = query[((size_t)(kh * QH_N + h0) * S_LEN + s) * D_DIM + d];
    float f1 = query[((size_t)(kh * QH_N + h0 + 2) * S_LEN + s) * D_DIM + d];
    unsigned long long b0 = __ballot(f0 >= 0.0f);
    unsigned long long b1 = __ballot(f1 >= 0.0f);
    if (lane == 0) {
      qs_sh[qh >> 1][qh & 1] = b0;
      qs_sh[2 + (qh >> 1)][qh & 1] = b1;
    }
    q_f16[h0][d]     = f2h(f0 * scale);
    q_f16[h0 + 2][d] = f2h(f1 * scale);
  }
  if (tid == 0) ncand_sh = 0;

  // ---- window part of the unified list ----
  int wlo = s - (wsz - 1); if (wlo < 0) wlo = 0;
  int nsink = wlo < SINK_N ? wlo : SINK_N;
  int nw = nsink + (s - wlo + 1);
  if (nw > MAXW) nw = MAXW;
  for (int e = tid; e < nw; e += 256)
    idx_sh[e] = (unsigned short)(e < nsink ? e : wlo + (e - nsink));
  __syncthreads();

  // ---- Stage 1: LSH scan over [SINK, s-wsz] -> append candidates at nw ----
  unsigned long long qs0[QH_N], qs1[QH_N];
#pragma unroll
  for (int h = 0; h < QH_N; h++) { qs0[h] = qs_sh[h][0]; qs1[h] = qs_sh[h][1]; }
  const unsigned long long* ksg = signs + (size_t)kh * S_LEN * 2;
  int lt_hi = s - wsz;  // inclusive
  for (int l0 = SINK_N; l0 <= lt_hi; l0 += 256) {
    int l = l0 + tid;
    bool match = false;
    if (l <= lt_hi) {
      ulonglong2 kk = *(const ulonglong2*)(ksg + 2 * l);
      int best = 0;
#pragma unroll
      for (int h = 0; h < QH_N; h++) {
        int m = 128 - __popcll(qs0[h] ^ kk.x) - __popcll(qs1[h] ^ kk.y);
        best = best > m ? best : m;
      }
      match = ((float)best > thresh);
    }
    unsigned long long m = __ballot(match);
    if (m) {
      int base = 0;
      if (lane == 0) base = atomicAdd(&ncand_sh, __popcll(m));
      base = __shfl(base, 0);
      if (match) {
        int pos = base + __popcll(m & ((1ull << lane) - 1ull));
        if (pos < MAXC) idx_sh[nw + pos] = (unsigned short)l;
      }
    }
  }
  __syncthreads();
  int nc = ncand_sh < MAXC ? ncand_sh : MAXC;
  int ntot = nw + nc;
  int ntot_pad = (ntot + 15) & ~15;
  for (int i = ntot + tid; i < ntot_pad; i += 256) idx_sh[i] = 0;
  __syncthreads();

  // ---- Stage 2: fp16 MFMA scoring -> packed fp16 ordered keys in LDS ----
  // Depth-1 pipelined: prefetch next tile's A-fragments while MFMA-ing the
  // current tile (idx_sh LDS read + 4x16B L2 gathers hide under ~100cy of
  // MFMA+pack instead of serializing ~320cy per tile).
  f16x8 bfrag[4];
  f16x8 bzero = {0, 0, 0, 0, 0, 0, 0, 0};
#pragma unroll
  for (int ks = 0; ks < 4; ks++)
    bfrag[ks] = (col < 4) ? *(const f16x8*)&q_f16[col][ks * 32 + quad * 8] : bzero;

  const unsigned short* kf_h = kf16 + ((size_t)kh << 11) * 128;
  unsigned int creg[NREG];     // 2 fp16 ordered keys per reg
#pragma unroll
  for (int i = 0; i < NREG; i++) creg[i] = 0u;

  for (int cb = 0; cb < 4; cb++) {
    int cbase = cb * CHUNK;
    int chunk_n = ntot_pad - cbase;
    if (chunk_n <= 0) break;
    if (chunk_n > CHUNK) chunk_n = CHUNK;
    int ntiles = chunk_n >> 4;
    int t = qh;
    if (t < ntiles) {
      const unsigned char* ab =
          (const unsigned char*)(kf_h +
                                 (size_t)idx_sh[cbase + t * 16 + col] * 128) +
          quad * 16;
      f16x8 a0 = *(const f16x8*)(ab + 0);
      f16x8 a1 = *(const f16x8*)(ab + 64);
      f16x8 a2 = *(const f16x8*)(ab + 128);
      f16x8 a3 = *(const f16x8*)(ab + 192);
      while (true) {
        int tn = t + QH_N;
        bool more = (tn < ntiles);
        f16x8 n0, n1, n2, n3;
        if (more) {
          const unsigned char* ab2 =
              (const unsigned char*)(kf_h +
                                     (size_t)idx_sh[cbase + tn * 16 + col] * 128) +
              quad * 16;
          n0 = *(const f16x8*)(ab2 + 0);
          n1 = *(const f16x8*)(ab2 + 64);
          n2 = *(const f16x8*)(ab2 + 128);
          n3 = *(const f16x8*)(ab2 + 192);
        }
        f32x4 acc = {0.f, 0.f, 0.f, 0.f};
        acc = __builtin_amdgcn_mfma_f32_16x16x32_f16(a0, bfrag[0], acc, 0, 0, 0);
        acc = __builtin_amdgcn_mfma_f32_16x16x32_f16(a1, bfrag[1], acc, 0, 0, 0);
        acc = __builtin_amdgcn_mfma_f32_16x16x32_f16(a2, bfrag[2], acc, 0, 0, 0);
        acc = __builtin_amdgcn_mfma_f32_16x16x32_f16(a3, bfrag[3], acc, 0, 0, 0);
        if (col < 4) {
          unsigned int k01 = pack_okey16(acc[0], acc[1]);
          unsigned int k23 = pack_okey16(acc[2], acc[3]);
          int off = t * 8 + quad * 2;
          buf[col * PLANE32 + off]     = k01;
          buf[col * PLANE32 + off + 1] = k23;
        }
        if (!more) break;
        a0 = n0; a1 = n1; a2 = n2; a3 = n3;
        t = tn;
      }
    }
    __syncthreads();
#pragma unroll
    for (int j = 0; j < 4; j++) {
      int m = j * 64 + lane;
      if (2 * m < chunk_n) creg[cb * 4 + j] = buf[qh * PLANE32 + m];
    }
    __syncthreads();
  }
  // reg i covers entries e = i*128 + 2*lane + {0,1}
  const int imax = (ntot + 127) >> 7;

  // per-wave scratch carved from this wave's plane (chunk keys are dead now)
  unsigned int*       histw = &buf[qh * PLANE32];                        // 256 u32
  unsigned long long* selq  = (unsigned long long*)&buf[qh * PLANE32 + 256]; // 208 u64

  // ---- cheap exact max: max over ALL scores == max over included set ----
  unsigned int mx16 = 0;
#pragma unroll
  for (int i = 0; i < NREG; i++) {
    if (i >= imax) break;
    unsigned int u = creg[i];
    int e0 = i * 128 + 2 * lane;
    unsigned int h0 = u & 0xFFFFu, h1 = u >> 16;
    if (e0 < ntot && h0 > mx16) mx16 = h0;
    if (e0 + 1 < ntot && h1 > mx16) mx16 = h1;
  }
#pragma unroll
  for (int off = 32; off > 0; off >>= 1) {
    unsigned int t = __shfl_down(mx16, off);
    mx16 = t > mx16 ? t : mx16;
  }
  mx16 = __shfl(mx16, 0);
  const float mxf = okinv16(mx16);

  // ---- Stage 3: per-wave exact top-k threshold (radix-256, 2 passes) ----
  bool selAll = (nc <= topk);
  unsigned int tkey = 0;
  bool useTie = false;
  int l_cut = S_LEN;
  if (!selAll) {
    unsigned int prefix = 0;
    int want = topk;
    for (int pass = 0; pass < 2; pass++) {
      int sh = 8 - pass * 8;
      {
        uint4 z = {0u, 0u, 0u, 0u};
        *(uint4*)&histw[lane * 4] = z;   // b128 clear, conflict-free
      }
      lds_fence();
#pragma unroll
      for (int i = 0; i < NREG; i++) {
        if (i >= imax) break;
        unsigned int u = creg[i];
        int e0 = i * 128 + 2 * lane;
#pragma unroll
        for (int h = 0; h < 2; h++) {
          int e = e0 + h;
          if (e >= nw && e < ntot) {
            unsigned int key = h ? (u >> 16) : (u & 0xFFFFu);
            bool match = (pass == 0) || ((key >> 8) == prefix);
            if (match) atomicAdd(&histw[(key >> sh) & 255u], 1u);
          }
        }
      }
      lds_fence();
      uint4 cc = *(const uint4*)&histw[lane * 4];
      unsigned int c0 = cc.x, c1 = cc.y, c2 = cc.z, c3 = cc.w;
      unsigned int S3 = c3, S2 = c2 + S3, S1 = c1 + S2, S0 = c0 + S1;
      unsigned int tot = S0;
      unsigned int suf = tot;
#pragma unroll
      for (int off = 1; off < 64; off <<= 1) {
        unsigned int t = __shfl_down(suf, off);
        if (lane + off < 64) suf += t;
      }
      unsigned long long mk = __ballot(suf >= (unsigned int)want);
      int L = 63 - __clzll(mk);
      unsigned int se = suf - tot;
      unsigned int s3 = S3 + se, s2 = S2 + se, s1 = S1 + se, s0 = S0 + se;
      int j; unsigned int above;
      unsigned int w = (unsigned int)want;
      if (s3 >= w)      { j = 3; above = s3 - c3; }
      else if (s2 >= w) { j = 2; above = s2 - c2; }
      else if (s1 >= w) { j = 1; above = s1 - c1; }
      else              { j = 0; above = s0 - c0; }
      int d_me = (lane << 2) | j;
      int wp_me = want - (int)above;
      int digit = __shfl(d_me, L);
      want = __shfl(wp_me, L);
      prefix = (prefix << 8) | (unsigned int)digit;
    }
    tkey = prefix;  // 16-bit ordered key of the 64th-largest candidate
    // exact tie handling (lowest l wins, matching lax.top_k)
    int cgt = 0, ceq = 0;
#pragma unroll
    for (int i = 0; i < NREG; i++) {
      if (i >= imax) break;
      unsigned int u = creg[i];
      int e0 = i * 128 + 2 * lane;
#pragma unroll
      for (int h = 0; h < 2; h++) {
        int e = e0 + h;
        if (e >= nw && e < ntot) {
          unsigned int key = h ? (u >> 16) : (u & 0xFFFFu);
          cgt += (key > tkey);
          ceq += (key == tkey);
        }
      }
    }
    // one packed shuffle chain instead of two (counts <= 2048 each)
    unsigned int cge = ((unsigned int)cgt << 16) | (unsigned int)ceq;
#pragma unroll
    for (int off = 32; off > 0; off >>= 1) cge += __shfl_down(cge, off);
    cge = __shfl(cge, 0);
    cgt = (int)(cge >> 16); ceq = (int)(cge & 0xFFFFu);
    int rem = topk - cgt;
    if (ceq > rem) {
      useTie = true;
      int lo = SINK_N, hi = lt_hi;   // candidates live in [SINK, s-wsz]
      while (lo < hi) {
        int mid = (lo + hi) >> 1;
        int cn = 0;
#pragma unroll
        for (int i = 0; i < NREG; i++) {
          if (i >= imax) break;
          unsigned int u = creg[i];
          int e0 = i * 128 + 2 * lane;
#pragma unroll
          for (int h = 0; h < 2; h++) {
            int e = e0 + h;
            if (e >= nw && e < ntot) {
              unsigned int key = h ? (u >> 16) : (u & 0xFFFFu);
              cn += (key == tkey && (int)idx_sh[e] <= mid);
            }
          }
        }
#pragma unroll
        for (int off = 32; off > 0; off >>= 1) cn += __shfl_down(cn, off);
        cn = __shfl(cn, 0);
        if (cn >= rem) hi = mid; else lo = mid + 1;
      }
      l_cut = lo;
    }
  }

  // ---- Stage 4: fused select + exp + compact (running register base) ----
  float sum = 0.0f;
  int bse = 0;
#pragma unroll
  for (int i = 0; i < NREG; i++) {
    if (i >= imax) break;
    unsigned int u = creg[i];
    int e0 = i * 128 + 2 * lane;
#pragma unroll
    for (int h = 0; h < 2; h++) {
      int e = e0 + h;
      bool act = false;
      float p = 0.f;
      if (e < ntot) {
        unsigned int key = h ? (u >> 16) : (u & 0xFFFFu);
        bool inc = (e < nw) || selAll;
        if (!inc)
          inc = (key > tkey) ||
                (key == tkey && (!useTie || (int)idx_sh[e] <= l_cut));
        if (inc) { act = true; p = __expf(okinv16(key) - mxf); sum += p; }
      }
      unsigned long long m = __ballot(act);
      if (act) {
        int pi = bse + __popcll(m & ((1ull << lane) - 1ull));
        selq[pi] = ((unsigned long long)idx_sh[e] << 32) |
                   (unsigned long long)__float_as_uint(p);
      }
      bse += (int)__popcll(m);
    }
  }

  int nsel = bse;
  int nsel8 = (nsel + 7) & ~7;
  if (lane < nsel8 - nsel) selq[nsel + lane] = 0ull;  // pad: p=0, idx=0
  lds_fence();

  // ---- Stage 5: PV via v_dot2_f32_f16; quarter-wave owns an entry PAIR,
  //      lane owns 8 dims (16B V loads), p packed fp16.
  //      Depth-1 pipelined; first prefetch issued BEFORE the softmax-sum
  //      shuffle chain so its L2 latency hides under the reduction. ----
  const int sub = lane & 15;        // dims 8*sub .. 8*sub+7
  const int quarter = lane >> 4;
  const uint4* vb4 = (const uint4*)(vf16 + ((size_t)kh << 11) * 64);

  // prefetch first entry pair + V rows (nsel >= 1 always: window has s itself)
  ulonglong2 sp = *(const ulonglong2*)&selq[2 * quarter];
  uint4 v0 = vb4[(size_t)(int)(sp.x >> 32) * 16 + sub];
  uint4 v1 = vb4[(size_t)(int)(sp.y >> 32) * 16 + sub];

#pragma unroll
  for (int off = 32; off > 0; off >>= 1) sum += __shfl_down(sum, off);
  sum = __shfl(sum, 0);
  float rinv = 1.0f / sum;

  float av[8] = {0.f, 0.f, 0.f, 0.f, 0.f, 0.f, 0.f, 0.f};
  int e = 0;
  while (true) {
    int en = e + 8;
    bool more = (en < nsel8);
    ulonglong2 spn;
    uint4 w0, w1;
    if (more) {
      spn = *(const ulonglong2*)&selq[en + 2 * quarter];
      w0 = vb4[(size_t)(int)(spn.x >> 32) * 16 + sub];
      w1 = vb4[(size_t)(int)(spn.y >> 32) * 16 + sub];
    }
    float p0 = __uint_as_float((unsigned int)sp.x);
    float p1 = __uint_as_float((unsigned int)sp.y);
    f16x2 ph = __builtin_bit_cast(f16x2, pkrtz_u32(p0, p1));
#define DOT2(comp, i0, i1)                                                   \
    {                                                                        \
      unsigned int lo_ = __builtin_amdgcn_perm(v1.comp, v0.comp, 0x05040100u); \
      unsigned int hi_ = __builtin_amdgcn_perm(v1.comp, v0.comp, 0x07060302u); \
      av[i0] = __builtin_amdgcn_fdot2(__builtin_bit_cast(f16x2, lo_), ph,    \
                                      av[i0], false);                        \
      av[i1] = __builtin_amdgcn_fdot2(__builtin_bit_cast(f16x2, hi_), ph,    \
                                      av[i1], false);                        \
    }
    DOT2(x, 0, 1) DOT2(y, 2, 3) DOT2(z, 4, 5) DOT2(w, 6, 7)
#undef DOT2
    if (!more) break;
    sp = spn; v0 = w0; v1 = w1; e = en;
  }
#pragma unroll
  for (int d = 0; d < 8; d++) {
    av[d] += __shfl_xor(av[d], 16);
    av[d] += __shfl_xor(av[d], 32);
  }
  if (lane < 16) {
    size_t o = (size_t)s * (H_N * D_DIM) + (size_t)(kh * QH_N + qh) * D_DIM
             + (size_t)sub * 8;
    f32x4 r0 = {av[0] * rinv, av[1] * rinv, av[2] * rinv, av[3] * rinv};
    f32x4 r1 = {av[4] * rinv, av[5] * rinv, av[6] * rinv, av[7] * rinv};
    __builtin_nontemporal_store(r0, (f32x4*)(out + o));
    __builtin_nontemporal_store(r1, (f32x4*)(out + o + 4));
  }
}

// ---------------------------------------------------------------------------
extern "C" void kernel_launch(void* const* d_in, const int* in_sizes, int n_in,
                              void* d_out, int out_size, void* d_ws, size_t ws_size,
                              hipStream_t stream) {
  const float* query = (const float*)d_in[0];
  const float* key   = (const float*)d_in[1];
  const float* value = (const float*)d_in[2];
  const float* thr   = (const float*)d_in[3];
  const int* p_topk  = (const int*)d_in[4];
  const int* p_wsz   = (const int*)d_in[5];
  float* out = (float*)d_out;

  // ws: k-signs 8192*16B = 128 KB | kf16 8192*256B = 2 MB | vf16 8192*256B = 2 MB
  char* ws = (char*)d_ws;
  unsigned long long* signs = (unsigned long long*)ws;
  unsigned short* kf16 = (unsigned short*)(ws + (size_t)KH_N * S_LEN * 16);
  unsigned int* vf16 = (unsigned int*)(ws + (size_t)KH_N * S_LEN * 16
                                          + (size_t)KH_N * S_LEN * 256);

  // 16384 k+v rows, 4 rows/wave, 4 waves/block -> 1024 blocks
  pack_kernel<<<1024, 256, 0, stream>>>(key, value, signs, kf16, vf16);

  attn_kernel<<<KH_N * S_LEN, 256, 0, stream>>>(
      query, thr, p_topk, p_wsz, signs, kf16, vf16, out);
}

// Round 2
// 251.248 us; speedup vs baseline: 1.0967x; 1.0967x over previous
//
#include <hip/hip_runtime.h>

// Problem constants (fixed by setup_inputs)
#define S_LEN   2048
#define D_DIM   128
#define KH_N    4
#define QH_N    4
#define H_N     (KH_N * QH_N)
#define SINK_N  16
#define MAXW    160    // >= window(128) + sink(16)
#define MAXC    1904   // >= S - SINK - window
#define MAXT    2048   // unified list capacity (s+1 <= 2048)
#define NREG    16     // u32 regs, 2 fp16 ordered keys each -> 2048 entries
#define CHUNK   1024   // rows scored per LDS chunk (r10: 512->1024, 4 barriers)
#define MAXSEL  208    // window(144) + top_k(64)
#define PLANE32 676    // u32 per plane (676 % 32 == 4 -> bank-skewed);
                       // phase A: 512 u32 packed chunk keys
                       // phase B: hist 256 u32 | selq 208 u64 (@ +256)
                       // tie scratch: 672 u32 (hist+selq area, both dead then)
#define TIECAP  672

typedef __attribute__((ext_vector_type(8))) _Float16 f16x8;
typedef __attribute__((ext_vector_type(2))) _Float16 f16x2;
typedef __attribute__((ext_vector_type(4))) float f32x4;

__device__ __forceinline__ void lds_fence() {
  asm volatile("s_waitcnt lgkmcnt(0)" ::: "memory");
}
__device__ __forceinline__ unsigned short f2h(float f) {
  _Float16 h = (_Float16)f;
  return __builtin_bit_cast(unsigned short, h);
}
// pack two fp32 -> two fp16 (RTZ) as u32
__device__ __forceinline__ unsigned int pkrtz_u32(float a, float b) {
  return __builtin_bit_cast(unsigned int, __builtin_amdgcn_cvt_pkrtz(a, b));
}
// pack two fp32 scores -> two 16-bit ordered keys (monotone with value)
__device__ __forceinline__ unsigned int pack_okey16(float a, float b) {
  unsigned int u = pkrtz_u32(a, b);
  unsigned int t = (u >> 15) & 0x00010001u;
  return u ^ ((t * 0x7FFFu) | 0x80008000u);
}
__device__ __forceinline__ float okinv16(unsigned int k) {  // k in low 16 bits
  unsigned short bits = (k & 0x8000u) ? (unsigned short)(k & 0x7FFFu)
                                      : (unsigned short)(~k & 0xFFFFu);
  return (float)__builtin_bit_cast(_Float16, bits);
}

// ---------------------------------------------------------------------------
// Kernel 1 (k/v only): one wave per 4 rows, row-type uniform per wave.
// [0,8192) k rows: sign words + fp16 plane. [8192,16384) v rows: fp16 plane.
// ---------------------------------------------------------------------------
__global__ __launch_bounds__(256) void pack_kernel(
    const float* __restrict__ k, const float* __restrict__ v,
    unsigned long long* __restrict__ signs,
    unsigned short* __restrict__ kf16, unsigned int* __restrict__ vf16) {
  const int wid  = (blockIdx.x * 256 + threadIdx.x) >> 6;
  const int lane = threadIdx.x & 63;
  const int rbase = wid * 4;
  const int KROWS = KH_N * S_LEN;           // 8192

  if (rbase < KROWS) {
    const float* src = k + (size_t)rbase * D_DIM;
    float a[4], b[4];
#pragma unroll
    for (int r = 0; r < 4; r++) {
      a[r] = src[r * D_DIM + lane];
      b[r] = src[r * D_DIM + 64 + lane];
    }
#pragma unroll
    for (int r = 0; r < 4; r++) {
      unsigned long long b0 = __ballot(a[r] >= 0.0f);
      unsigned long long b1 = __ballot(b[r] >= 0.0f);
      if (lane == 0) {
        signs[(size_t)(rbase + r) * 2]     = b0;
        signs[(size_t)(rbase + r) * 2 + 1] = b1;
      }
      unsigned short* rb = kf16 + (size_t)(rbase + r) * 128;
      rb[lane]      = f2h(a[r]);
      rb[64 + lane] = f2h(b[r]);
    }
  } else {
    int vr = rbase - KROWS;
    const float* src = v + (size_t)vr * D_DIM;
    float2 f2[4];
#pragma unroll
    for (int r = 0; r < 4; r++)
      f2[r] = *(const float2*)(src + r * D_DIM + lane * 2);
#pragma unroll
    for (int r = 0; r < 4; r++) {
      unsigned int pk = (unsigned int)f2h(f2[r].x) |
                        ((unsigned int)f2h(f2[r].y) << 16);
      vf16[(size_t)(vr + r) * 64 + lane] = pk;
    }
  }
}

// ---------------------------------------------------------------------------
// Kernel 2: one block (4 waves) per (kh, s); wave == qh within the GQA group.
// xcd swizzle (blockIdx&7) -> each kh owned by 2 XCDs (halved FETCH in r8).
// fp16 packed score keys: NREG=16, radix-256 in 2 passes.
// r9 POST-MORTEM: manual depth-1 pipelining of the gather loops REGRESSED
// (195->218us, occupancy 75->54, VGPR 36->44) -- reverted to the simple
// strided loops; the compiler's own schedule was better.
// r10: cut VALU instruction count instead:
//  - cgt/ceq pass deleted (radix select already yields rem=want, ceq=c_j@L)
//  - tie break: 11-pass binary search -> 1 compact pass + LDS rank-select
//  - CHUNK 512->1024: Stage-2 barriers 8 -> 4
// ---------------------------------------------------------------------------
__global__ __launch_bounds__(256, 5) void attn_kernel(
    const float* __restrict__ query, const float* __restrict__ thr,
    const int* __restrict__ p_topk, const int* __restrict__ p_wsz,
    const unsigned long long* __restrict__ signs,
    const unsigned short* __restrict__ kf16,
    const unsigned int* __restrict__ vf16,
    float* __restrict__ out) {
  const int xcd  = blockIdx.x & 7;
  const int kh   = xcd >> 1;
  const int s    = (S_LEN - 1) - (((blockIdx.x >> 3) << 1) | (xcd & 1));
  const int tid  = threadIdx.x;
  const int lane = tid & 63;
  const int qh   = tid >> 6;
  const int col  = lane & 15;
  const int quad = lane >> 4;

  __shared__ __align__(16) unsigned int buf[QH_N * PLANE32]; // 10816 B
  __shared__ __align__(16) unsigned short q_f16[QH_N][136];  // 1088 B
  __shared__ unsigned short idx_sh[MAXT];                    // 4096 B
  __shared__ unsigned long long qs_sh[QH_N][2];
  __shared__ int ncand_sh;

  const int   topk   = *p_topk;   // 64
  const int   wsz    = *p_wsz;    // 128
  const float thresh = thr[kh];   // 70.0
  const float scale  = 0.088388347648318447f;  // 1/sqrt(128)

  // ---- load q rows; build q_f16 + q sign words (ballot == sign word) ----
  {
    int h0 = tid >> 7, d = tid & 127;
    float f0 = query[((size_t)(kh * QH_N + h0) * S_LEN + s) * D_DIM + d];
    float f1 = query[((size_t)(kh * QH_N + h0 + 2) * S_LEN + s) * D_DIM + d];
    unsigned long long b0 = __ballot(f0 >= 0.0f);
    unsigned long long b1 = __ballot(f1 >= 0.0f);
    if (lane == 0) {
      qs_sh[qh >> 1][qh & 1] = b0;
      qs_sh[2 + (qh >> 1)][qh & 1] = b1;
    }
    q_f16[h0][d]     = f2h(f0 * scale);
    q_f16[h0 + 2][d] = f2h(f1 * scale);
  }
  if (tid == 0) ncand_sh = 0;

  // ---- window part of the unified list ----
  int wlo = s - (wsz - 1); if (wlo < 0) wlo = 0;
  int nsink = wlo < SINK_N ? wlo : SINK_N;
  int nw = nsink + (s - wlo + 1);
  if (nw > MAXW) nw = MAXW;
  for (int e = tid; e < nw; e += 256)
    idx_sh[e] = (unsigned short)(e < nsink ? e : wlo + (e - nsink));
  __syncthreads();

  // ---- Stage 1: LSH scan over [SINK, s-wsz] -> append candidates at nw ----
  unsigned long long qs0[QH_N], qs1[QH_N];
#pragma unroll
  for (int h = 0; h < QH_N; h++) { qs0[h] = qs_sh[h][0]; qs1[h] = qs_sh[h][1]; }
  const unsigned long long* ksg = signs + (size_t)kh * S_LEN * 2;
  int lt_hi = s - wsz;  // inclusive
  for (int l0 = SINK_N; l0 <= lt_hi; l0 += 256) {
    int l = l0 + tid;
    bool match = false;
    if (l <= lt_hi) {
      ulonglong2 kk = *(const ulonglong2*)(ksg + 2 * l);
      int best = 0;
#pragma unroll
      for (int h = 0; h < QH_N; h++) {
        int m = 128 - __popcll(qs0[h] ^ kk.x) - __popcll(qs1[h] ^ kk.y);
        best = best > m ? best : m;
      }
      match = ((float)best > thresh);
    }
    unsigned long long m = __ballot(match);
    if (m) {
      int base = 0;
      if (lane == 0) base = atomicAdd(&ncand_sh, __popcll(m));
      base = __shfl(base, 0);
      if (match) {
        int pos = base + __popcll(m & ((1ull << lane) - 1ull));
        if (pos < MAXC) idx_sh[nw + pos] = (unsigned short)l;
      }
    }
  }
  __syncthreads();
  int nc = ncand_sh < MAXC ? ncand_sh : MAXC;
  int ntot = nw + nc;
  int ntot_pad = (ntot + 15) & ~15;
  for (int i = ntot + tid; i < ntot_pad; i += 256) idx_sh[i] = 0;
  __syncthreads();

  // ---- Stage 2: fp16 MFMA scoring -> packed fp16 ordered keys in LDS ----
  f16x8 bfrag[4];
  f16x8 bzero = {0, 0, 0, 0, 0, 0, 0, 0};
#pragma unroll
  for (int ks = 0; ks < 4; ks++)
    bfrag[ks] = (col < 4) ? *(const f16x8*)&q_f16[col][ks * 32 + quad * 8] : bzero;

  const unsigned short* kf_h = kf16 + ((size_t)kh << 11) * 128;
  unsigned int creg[NREG];     // 2 fp16 ordered keys per reg
#pragma unroll
  for (int i = 0; i < NREG; i++) creg[i] = 0u;

  for (int cb = 0; cb < 2; cb++) {
    int cbase = cb * CHUNK;
    int chunk_n = ntot_pad - cbase;
    if (chunk_n <= 0) break;
    if (chunk_n > CHUNK) chunk_n = CHUNK;
    int ntiles = chunk_n >> 4;
    for (int t = qh; t < ntiles; t += QH_N) {
      int tb = cbase + t * 16;
      int krow = idx_sh[tb + col];
      const unsigned char* ab =
          (const unsigned char*)(kf_h + (size_t)krow * 128) + quad * 16;
      f16x8 a0 = *(const f16x8*)(ab + 0);
      f16x8 a1 = *(const f16x8*)(ab + 64);
      f16x8 a2 = *(const f16x8*)(ab + 128);
      f16x8 a3 = *(const f16x8*)(ab + 192);
      f32x4 acc = {0.f, 0.f, 0.f, 0.f};
      acc = __builtin_amdgcn_mfma_f32_16x16x32_f16(a0, bfrag[0], acc, 0, 0, 0);
      acc = __builtin_amdgcn_mfma_f32_16x16x32_f16(a1, bfrag[1], acc, 0, 0, 0);
      acc = __builtin_amdgcn_mfma_f32_16x16x32_f16(a2, bfrag[2], acc, 0, 0, 0);
      acc = __builtin_amdgcn_mfma_f32_16x16x32_f16(a3, bfrag[3], acc, 0, 0, 0);
      if (col < 4) {
        unsigned int k01 = pack_okey16(acc[0], acc[1]);
        unsigned int k23 = pack_okey16(acc[2], acc[3]);
        int off = ((tb - cbase) >> 1) + quad * 2;
        buf[col * PLANE32 + off]     = k01;
        buf[col * PLANE32 + off + 1] = k23;
      }
    }
    __syncthreads();
#pragma unroll
    for (int j = 0; j < 8; j++) {
      int m = j * 64 + lane;
      if (2 * m < chunk_n) creg[cb * 8 + j] = buf[qh * PLANE32 + m];
    }
    __syncthreads();
  }
  // reg i covers entries e = i*128 + 2*lane + {0,1}
  const int imax = (ntot + 127) >> 7;

  // per-wave scratch carved from this wave's plane (chunk keys are dead now)
  unsigned int*       histw = &buf[qh * PLANE32];                        // 256 u32
  unsigned long long* selq  = (unsigned long long*)&buf[qh * PLANE32 + 256]; // 208 u64

  // ---- cheap exact max: max over ALL scores == max over included set ----
  unsigned int mx16 = 0;
#pragma unroll
  for (int i = 0; i < NREG; i++) {
    if (i >= imax) break;
    unsigned int u = creg[i];
    int e0 = i * 128 + 2 * lane;
    unsigned int h0 = u & 0xFFFFu, h1 = u >> 16;
    if (e0 < ntot && h0 > mx16) mx16 = h0;
    if (e0 + 1 < ntot && h1 > mx16) mx16 = h1;
  }
#pragma unroll
  for (int off = 32; off > 0; off >>= 1) {
    unsigned int t = __shfl_down(mx16, off);
    mx16 = t > mx16 ? t : mx16;
  }
  mx16 = __shfl(mx16, 0);
  const float mxf = okinv16(mx16);

  // ---- Stage 3: per-wave exact top-k threshold (radix-256, 2 passes) ----
  bool selAll = (nc <= topk);
  unsigned int tkey = 0;
  bool useTie = false;
  int l_cut = S_LEN;
  if (!selAll) {
    unsigned int prefix = 0;
    int want = topk;
    unsigned int ceq = 0;   // after pass 1: count of candidates == tkey
    for (int pass = 0; pass < 2; pass++) {
      int sh = 8 - pass * 8;
      {
        uint4 z = {0u, 0u, 0u, 0u};
        *(uint4*)&histw[lane * 4] = z;   // b128 clear, conflict-free
      }
      lds_fence();
#pragma unroll
      for (int i = 0; i < NREG; i++) {
        if (i >= imax) break;
        unsigned int u = creg[i];
        int e0 = i * 128 + 2 * lane;
#pragma unroll
        for (int h = 0; h < 2; h++) {
          int e = e0 + h;
          if (e >= nw && e < ntot) {
            unsigned int key = h ? (u >> 16) : (u & 0xFFFFu);
            bool match = (pass == 0) || ((key >> 8) == prefix);
            if (match) atomicAdd(&histw[(key >> sh) & 255u], 1u);
          }
        }
      }
      lds_fence();
      uint4 cc = *(const uint4*)&histw[lane * 4];
      unsigned int c0 = cc.x, c1 = cc.y, c2 = cc.z, c3 = cc.w;
      unsigned int S3 = c3, S2 = c2 + S3, S1 = c1 + S2, S0 = c0 + S1;
      unsigned int tot = S0;
      unsigned int suf = tot;
#pragma unroll
      for (int off = 1; off < 64; off <<= 1) {
        unsigned int t = __shfl_down(suf, off);
        if (lane + off < 64) suf += t;
      }
      unsigned long long mk = __ballot(suf >= (unsigned int)want);
      int L = 63 - __clzll(mk);
      unsigned int se = suf - tot;
      unsigned int s3 = S3 + se, s2 = S2 + se, s1 = S1 + se, s0 = S0 + se;
      int j; unsigned int above, csel;
      unsigned int w = (unsigned int)want;
      if (s3 >= w)      { j = 3; above = s3 - c3; csel = c3; }
      else if (s2 >= w) { j = 2; above = s2 - c2; csel = c2; }
      else if (s1 >= w) { j = 1; above = s1 - c1; csel = c1; }
      else              { j = 0; above = s0 - c0; csel = c0; }
      int d_me = (lane << 2) | j;
      int wp_me = want - (int)above;
      int digit = __shfl(d_me, L);
      want = __shfl(wp_me, L);
      ceq = (unsigned int)__shfl((int)csel, L);
      prefix = (prefix << 8) | (unsigned int)digit;
    }
    tkey = prefix;  // 16-bit ordered key of the 64th-largest candidate
    // rem/ceq come FREE from the radix state: want == topk - cgt; ceq == c_j@L
    int rem = want;
    if ((int)ceq > rem) {
      // exact tie handling (lowest l wins, matching lax.top_k)
      useTie = true;
      if ((int)ceq <= TIECAP) {
        // fast path: compact tied l's, then rank-select rem-th smallest
        unsigned int* tls = histw;   // 672 u32 scratch (hist+selq, both dead)
        int tb = 0;
#pragma unroll
        for (int i = 0; i < NREG; i++) {
          if (i >= imax) break;
          unsigned int u = creg[i];
          int e0 = i * 128 + 2 * lane;
#pragma unroll
          for (int h = 0; h < 2; h++) {
            int e = e0 + h;
            bool tied = false;
            if (e >= nw && e < ntot) {
              unsigned int key = h ? (u >> 16) : (u & 0xFFFFu);
              tied = (key == tkey);
            }
            unsigned long long m = __ballot(tied);
            if (tied) {
              int pos = tb + __popcll(m & ((1ull << lane) - 1ull));
              tls[pos] = (unsigned int)idx_sh[e];
            }
            tb += (int)__popcll(m);
          }
        }
        lds_fence();
        // l values are unique -> exactly one has rank rem-1
        unsigned int lcut = (unsigned int)S_LEN;
        for (int i = lane; i < (int)ceq; i += 64) {
          unsigned int v = tls[i];
          int rank = 0;
          for (int j2 = 0; j2 < (int)ceq; j2++) rank += (tls[j2] < v);
          if (rank == rem - 1) lcut = v;
        }
#pragma unroll
        for (int off = 32; off > 0; off >>= 1) {
          unsigned int t = __shfl_down(lcut, off);
          lcut = t < lcut ? t : lcut;
        }
        l_cut = (int)__shfl((int)lcut, 0);
      } else {
        // cold fallback: binary search over l (pathological mass-tie only)
        int lo = SINK_N, hi = lt_hi;
        while (lo < hi) {
          int mid = (lo + hi) >> 1;
          int cn = 0;
#pragma unroll
          for (int i = 0; i < NREG; i++) {
            if (i >= imax) break;
            unsigned int u = creg[i];
            int e0 = i * 128 + 2 * lane;
#pragma unroll
            for (int h = 0; h < 2; h++) {
              int e = e0 + h;
              if (e >= nw && e < ntot) {
                unsigned int key = h ? (u >> 16) : (u & 0xFFFFu);
                cn += (key == tkey && (int)idx_sh[e] <= mid);
              }
            }
          }
#pragma unroll
          for (int off = 32; off > 0; off >>= 1) cn += __shfl_down(cn, off);
          cn = __shfl(cn, 0);
          if (cn >= rem) hi = mid; else lo = mid + 1;
        }
        l_cut = lo;
      }
    }
  }

  // ---- Stage 4: fused select + exp + compact (running register base) ----
  float sum = 0.0f;
  int bse = 0;
#pragma unroll
  for (int i = 0; i < NREG; i++) {
    if (i >= imax) break;
    unsigned int u = creg[i];
    int e0 = i * 128 + 2 * lane;
#pragma unroll
    for (int h = 0; h < 2; h++) {
      int e = e0 + h;
      bool act = false;
      float p = 0.f;
      if (e < ntot) {
        unsigned int key = h ? (u >> 16) : (u & 0xFFFFu);
        bool inc = (e < nw) || selAll;
        if (!inc)
          inc = (key > tkey) ||
                (key == tkey && (!useTie || (int)idx_sh[e] <= l_cut));
        if (inc) { act = true; p = __expf(okinv16(key) - mxf); sum += p; }
      }
      unsigned long long m = __ballot(act);
      if (act) {
        int pi = bse + __popcll(m & ((1ull << lane) - 1ull));
        selq[pi] = ((unsigned long long)idx_sh[e] << 32) |
                   (unsigned long long)__float_as_uint(p);
      }
      bse += (int)__popcll(m);
    }
  }
#pragma unroll
  for (int off = 32; off > 0; off >>= 1) sum += __shfl_down(sum, off);
  sum = __shfl(sum, 0);
  float rinv = 1.0f / sum;

  int nsel = bse;
  int nsel8 = (nsel + 7) & ~7;
  if (lane < nsel8 - nsel) selq[nsel + lane] = 0ull;  // pad: p=0, idx=0
  lds_fence();

  // ---- Stage 5: PV via v_dot2_f32_f16; quarter-wave owns an entry PAIR,
  //      lane owns 8 dims (16B V loads), p packed fp16 ----
  const int sub = lane & 15;        // dims 8*sub .. 8*sub+7
  const int quarter = lane >> 4;
  float av[8] = {0.f, 0.f, 0.f, 0.f, 0.f, 0.f, 0.f, 0.f};
  const uint4* vb4 = (const uint4*)(vf16 + ((size_t)kh << 11) * 64);
  for (int e = 0; e < nsel8; e += 8) {
    ulonglong2 sp = *(const ulonglong2*)&selq[e + 2 * quarter];
    float p0 = __uint_as_float((unsigned int)sp.x);
    float p1 = __uint_as_float((unsigned int)sp.y);
    int l0 = (int)(sp.x >> 32), l1 = (int)(sp.y >> 32);
    f16x2 ph = __builtin_bit_cast(f16x2, pkrtz_u32(p0, p1));
    uint4 v0 = vb4[(size_t)l0 * 16 + sub];
    uint4 v1 = vb4[(size_t)l1 * 16 + sub];
#define DOT2(comp, i0, i1)                                                   \
    {                                                                        \
      unsigned int lo_ = __builtin_amdgcn_perm(v1.comp, v0.comp, 0x05040100u); \
      unsigned int hi_ = __builtin_amdgcn_perm(v1.comp, v0.comp, 0x07060302u); \
      av[i0] = __builtin_amdgcn_fdot2(__builtin_bit_cast(f16x2, lo_), ph,    \
                                      av[i0], false);                        \
      av[i1] = __builtin_amdgcn_fdot2(__builtin_bit_cast(f16x2, hi_), ph,    \
                                      av[i1], false);                        \
    }
    DOT2(x, 0, 1) DOT2(y, 2, 3) DOT2(z, 4, 5) DOT2(w, 6, 7)
#undef DOT2
  }
#pragma unroll
  for (int d = 0; d < 8; d++) {
    av[d] += __shfl_xor(av[d], 16);
    av[d] += __shfl_xor(av[d], 32);
  }
  if (lane < 16) {
    size_t o = (size_t)s * (H_N * D_DIM) + (size_t)(kh * QH_N + qh) * D_DIM
             + (size_t)sub * 8;
    f32x4 r0 = {av[0] * rinv, av[1] * rinv, av[2] * rinv, av[3] * rinv};
    f32x4 r1 = {av[4] * rinv, av[5] * rinv, av[6] * rinv, av[7] * rinv};
    __builtin_nontemporal_store(r0, (f32x4*)(out + o));
    __builtin_nontemporal_store(r1, (f32x4*)(out + o + 4));
  }
}

// ---------------------------------------------------------------------------
extern "C" void kernel_launch(void* const* d_in, const int* in_sizes, int n_in,
                              void* d_out, int out_size, void* d_ws, size_t ws_size,
                              hipStream_t stream) {
  const float* query = (const float*)d_in[0];
  const float* key   = (const float*)d_in[1];
  const float* value = (const float*)d_in[2];
  const float* thr   = (const float*)d_in[3];
  const int* p_topk  = (const int*)d_in[4];
  const int* p_wsz   = (const int*)d_in[5];
  float* out = (float*)d_out;

  // ws: k-signs 8192*16B = 128 KB | kf16 8192*256B = 2 MB | vf16 8192*256B = 2 MB
  char* ws = (char*)d_ws;
  unsigned long long* signs = (unsigned long long*)ws;
  unsigned short* kf16 = (unsigned short*)(ws + (size_t)KH_N * S_LEN * 16);
  unsigned int* vf16 = (unsigned int*)(ws + (size_t)KH_N * S_LEN * 16
                                          + (size_t)KH_N * S_LEN * 256);

  // 16384 k+v rows, 4 rows/wave, 4 waves/block -> 1024 blocks
  pack_kernel<<<1024, 256, 0, stream>>>(key, value, signs, kf16, vf16);

  attn_kernel<<<KH_N * S_LEN, 256, 0, stream>>>(
      query, thr, p_topk, p_wsz, signs, kf16, vf16, out);
}